// Round 4
// baseline (174.971 us; speedup 1.0000x reference)
//
#include <hip/hip_runtime.h>
#include <cmath>

#define SEQ    2048
#define DMODEL 1024
#define NHEADS 16
#define DK     64
#define MROWS  4096   // B*S
#define KBUF   4096   // flash LDS double-buffer offset (64*64 shorts)

typedef __bf16 bf16x8 __attribute__((ext_vector_type(8)));
typedef float  f32x4  __attribute__((ext_vector_type(4)));
typedef short  s16x4  __attribute__((ext_vector_type(4)));

__device__ __forceinline__ unsigned short f2bf(float f) {
    union { float f; unsigned u; } v; v.f = f;
    unsigned r = v.u + 0x7fffu + ((v.u >> 16) & 1u);   // RNE
    return (unsigned short)(r >> 16);
}

__device__ __forceinline__ void async16(const unsigned short* g, unsigned short* l) {
    __builtin_amdgcn_global_load_lds(
        (const __attribute__((address_space(1))) unsigned int*)(g),
        (__attribute__((address_space(3))) unsigned int*)(l),
        16, 0, 0);
}

// XOR-granule swizzle: pitch 64 shorts, 8-short (16B) granules, granule g of
// row r lives at slot g ^ (r&7).  All flash LDS accesses map 8 lanes to each
// 4-bank group per op -> conflict-free (R13: was 5.5M conflict cycles).
__device__ __forceinline__ int swz64(int row, int col) {
    return (row << 6) + ((((col >> 3) ^ row) & 7) << 3) + (col & 7);
}

// ---------------------------------------------------------------------------
// fp32 -> bf16 conversion of x, Wq|Wk|Wv (packed), Wo
// ---------------------------------------------------------------------------
__global__ __launch_bounds__(256)
void convert_kernel(const float* __restrict__ x,
                    const float* __restrict__ wq, const float* __restrict__ wk,
                    const float* __restrict__ wv, const float* __restrict__ wo,
                    unsigned short* __restrict__ xb,
                    unsigned short* __restrict__ wqkvb,
                    unsigned short* __restrict__ wob)
{
    const unsigned e = (blockIdx.x * 256u + threadIdx.x) * 8u;
    const float* src; unsigned short* dst; unsigned off;
    if      (e < 4194304u) { src = x;  dst = xb;             off = e;            }
    else if (e < 5242880u) { src = wq; dst = wqkvb;          off = e - 4194304u; }
    else if (e < 6291456u) { src = wk; dst = wqkvb+1048576u; off = e - 5242880u; }
    else if (e < 7340032u) { src = wv; dst = wqkvb+2097152u; off = e - 6291456u; }
    else                   { src = wo; dst = wob;            off = e - 7340032u; }
    float4 a = *(const float4*)(src + off);
    float4 b = *(const float4*)(src + off + 4);
    ushort4 u0, u1;
    u0.x=f2bf(a.x); u0.y=f2bf(a.y); u0.z=f2bf(a.z); u0.w=f2bf(a.w);
    u1.x=f2bf(b.x); u1.y=f2bf(b.y); u1.z=f2bf(b.z); u1.w=f2bf(b.w);
    *(ushort4*)(dst + off)     = u0;
    *(ushort4*)(dst + off + 4) = u1;
}

// ---------------------------------------------------------------------------
// bf16 MFMA GEMM: Y = A[M][1024] @ B[NCOLS][1024]^T.  TM x TN tiles, BK=64,
// single-buffered async16 (m97 structure).  MINW = launch_bounds min waves/EU.
// R15: O-proj 64x64 -> 128x64 (16 MFMA : 6 async16 per K-step vs 8:8;
// grid (16,32)=512 = 2/CU).  QKV stays 128x128 @ 3/CU.
// MODE 0: fp32 row-major out (O-proj).
// MODE 1: QKV split: cols <2048 -> RoPE + bf16 QK buf; cols >=2048 -> V^T.
// ---------------------------------------------------------------------------
template<int TM, int TN, int NCOLS, int MODE, int MINW>
__global__ __launch_bounds__(256, MINW)
void gemm_mfma_bt(const unsigned short* __restrict__ A,
                  const unsigned short* __restrict__ B,
                  void* __restrict__ Yqk,
                  unsigned short* __restrict__ Yvt)
{
    constexpr int AINST = TM / 32;      // A async16 insts per thread
    constexpr int BINST = TN / 32;      // B async16 insts per thread
    constexpr int MT    = TM / 32;      // 16-row frags per wave (TM/2 /16)
    constexpr int NT    = TN / 32;      // 16-col frags per wave

    __shared__ unsigned short As[TM * 64];
    __shared__ unsigned short Bs[TN * 64];

    const int t    = threadIdx.x;
    const int w    = t >> 6;
    const int lane = t & 63;
    const int lq   = lane >> 4;
    const int ln   = lane & 15;
    const int m0   = blockIdx.y * TM;
    const int n0   = blockIdx.x * TN;

    const int mrow0 = (w & 1) * (TM / 2);      // wave tile: TM/2 x TN/2
    const int ncol0 = (w >> 1) * (TN / 2);

    const int srow  = w*8 + (lane >> 3);
    const int gslot = (lane & 7) ^ (lane >> 3);

    const unsigned short* gA[AINST]; unsigned short* lA[AINST];
    #pragma unroll
    for (int i = 0; i < AINST; ++i) {
        gA[i] = A + (size_t)(m0 + i*32 + srow) * 1024 + gslot*8;
        lA[i] = As + (i*32 + w*8) * 64;
    }
    const unsigned short* gB[BINST]; unsigned short* lB[BINST];
    #pragma unroll
    for (int i = 0; i < BINST; ++i) {
        gB[i] = B + (size_t)(n0 + i*32 + srow) * 1024 + gslot*8;
        lB[i] = Bs + (i*32 + w*8) * 64;
    }

    f32x4 acc[MT][NT];
    #pragma unroll
    for (int mt = 0; mt < MT; ++mt)
        #pragma unroll
        for (int nt = 0; nt < NT; ++nt)
            #pragma unroll
            for (int r = 0; r < 4; ++r) acc[mt][nt][r] = 0.0f;

    const int fsw = (ln & 7);

    for (int k0 = 0; k0 < 1024; k0 += 64) {
        __syncthreads();
        #pragma unroll
        for (int i = 0; i < AINST; ++i) async16(gA[i] + k0, lA[i]);
        #pragma unroll
        for (int i = 0; i < BINST; ++i) async16(gB[i] + k0, lB[i]);
        __syncthreads();
        #pragma unroll
        for (int kh = 0; kh < 2; ++kh) {
            const int g  = kh*4 + lq;
            const int ps = (g ^ fsw) * 8;
            bf16x8 af[MT], bf[NT];
            #pragma unroll
            for (int mt = 0; mt < MT; ++mt)
                af[mt] = *(const bf16x8*)&As[(mrow0 + mt*16 + ln)*64 + ps];
            #pragma unroll
            for (int nt = 0; nt < NT; ++nt)
                bf[nt] = *(const bf16x8*)&Bs[(ncol0 + nt*16 + ln)*64 + ps];
            #pragma unroll
            for (int mt = 0; mt < MT; ++mt)
                #pragma unroll
                for (int nt = 0; nt < NT; ++nt)
                    acc[mt][nt] = __builtin_amdgcn_mfma_f32_16x16x32_bf16(
                                      af[mt], bf[nt], acc[mt][nt], 0, 0, 0);
        }
    }

    if (MODE == 0) {
        float* Yf = (float*)Yqk;
        #pragma unroll
        for (int nt = 0; nt < NT; ++nt) {
            const int col = n0 + ncol0 + nt*16 + ln;
            #pragma unroll
            for (int mt = 0; mt < MT; ++mt) {
                const int row0 = m0 + mrow0 + mt*16 + lq*4;
                #pragma unroll
                for (int r = 0; r < 4; ++r)
                    Yf[(size_t)(row0 + r) * NCOLS + col] = acc[mt][nt][r];
            }
        }
    } else if (n0 < 2048) {
        // QK region: RoPE, bf16 row-major LD 2048
        unsigned short* Yb = (unsigned short*)Yqk;
        const float LOG_T = 9.210340371976184f / 32.0f;
        #pragma unroll
        for (int nt = 0; nt < NT; ++nt) {
            const int col = n0 + ncol0 + nt*16 + ln;
            const float fr = __expf(-(float)((col & 63) >> 1) * LOG_T);
            #pragma unroll
            for (int mt = 0; mt < MT; ++mt) {
                const int row0 = m0 + mrow0 + mt*16 + lq*4;
                #pragma unroll
                for (int r = 0; r < 4; ++r) {
                    const float v = acc[mt][nt][r];
                    float sn, cs;
                    __sincosf((float)((row0 + r) & (SEQ - 1)) * fr, &sn, &cs);
                    const float p = __shfl_xor(v, 1);
                    const float outv = ((ln & 1) == 0) ? (v*cs - p*sn) : (p*sn + v*cs);
                    Yb[(size_t)(row0 + r) * 2048 + col] = f2bf(outv);
                }
            }
        }
    } else {
        // V region: write transposed [b][d][s]; lane's 4 rows contiguous in s
        #pragma unroll
        for (int nt = 0; nt < NT; ++nt) {
            const int d = (n0 - 2048) + ncol0 + nt*16 + ln;
            #pragma unroll
            for (int mt = 0; mt < MT; ++mt) {
                const int row0 = m0 + mrow0 + mt*16 + lq*4;
                const int b = row0 >> 11;
                const int s = row0 & 2047;
                ushort4 o;
                o.x = f2bf(acc[mt][nt][0]); o.y = f2bf(acc[mt][nt][1]);
                o.z = f2bf(acc[mt][nt][2]); o.w = f2bf(acc[mt][nt][3]);
                *(ushort4*)&Yvt[((size_t)b*1024 + d) * 2048 + s] = o;
            }
        }
    }
}

// ---------------------------------------------------------------------------
// R15 flash core: double-buffered K/V LDS, ONE barrier per KV tile (was 2).
// Iter kt: write tile kt+1 -> buf[cur^1] (safe: barrier(kt-1) drained its
// readers), prefetch regs kt+2, compute on buf[cur], barrier, swap.  The
// ds-writes and global prefetch drain under the MFMA/softmax of tile kt.
// Q staged in buf1; its reads complete before buf1's first write (2nd
// prologue barrier).  Max-free softmax -> partials are pure sums.
// ---------------------------------------------------------------------------
__device__ __forceinline__ float flash_core(
    const unsigned short* __restrict__ Qrow,   // Q base of this q-tile (LD 2048)
    const unsigned short* __restrict__ Kgb,    // K base for this b (LD 2048)
    const unsigned short* __restrict__ Vgb,    // V^T base for this (b,head)
    unsigned short* Kt, unsigned short* Vt,    // each 2 x 64 x 64
    const int qb, const int kt0, const int kt1,   // kt range inclusive; kt1<kt0 => empty
    const int t, const int w, const int lq, const int ln,
    f32x4 (&oacc)[4])
{
    const int sr = t >> 2;            // staging row 0..63
    const int sc = (t & 3) * 16;      // staging col 0,16,32,48
    const int ks = t & 3;             // this thread's key-subtile for V staging
    const float SCALE2 = 0.125f * 1.4426950408889634f;   // 1/sqrt(dk) * log2e
    const bool any = (kt0 <= kt1);

    {   // stage Q tile -> Kt buf1 (first K-write to buf1 is iter kt0+1)
        const unsigned short* qp = Qrow + (size_t)sr * 2048 + sc;
        *(float4*)&Kt[KBUF + swz64(sr, sc)]     = *(const float4*)qp;
        *(float4*)&Kt[KBUF + swz64(sr, sc + 8)] = *(const float4*)(qp + 8);
    }
    float4 kA, kB, vA, vB;
    if (any) {   // preload first K/V^T tile into registers
        const unsigned short* kp = Kgb + (size_t)(kt0*64 + sr) * 2048 + sc;
        kA = *(const float4*)kp;  kB = *(const float4*)(kp + 8);
        const unsigned short* vp = Vgb + (size_t)sr * 2048 + kt0*64 + sc;
        vA = *(const float4*)vp;  vB = *(const float4*)(vp + 8);
    }
    __syncthreads();                    // Q visible
    const bf16x8 qf0 = *(const bf16x8*)&Kt[KBUF + swz64(w*16 + ln, lq*8)];
    const bf16x8 qf1 = *(const bf16x8*)&Kt[KBUF + swz64(w*16 + ln, 32 + lq*8)];

    if (any) {   // write tile kt0 -> buf0 (disjoint from Q reads in buf1)
        *(float4*)&Kt[swz64(sr, sc)]     = kA;
        *(float4*)&Kt[swz64(sr, sc + 8)] = kB;
        const ushort4* va4 = (const ushort4*)&vA;
        const ushort4* vb4 = (const ushort4*)&vB;
        *(ushort4*)&Vt[swz64(sr, ks*4 +  0)] = va4[0];
        *(ushort4*)&Vt[swz64(sr, ks*4 + 16)] = va4[1];
        *(ushort4*)&Vt[swz64(sr, ks*4 + 32)] = vb4[0];
        *(ushort4*)&Vt[swz64(sr, ks*4 + 48)] = vb4[1];
        if (kt0 < kt1) {                // preload regs for kt0+1
            const unsigned short* kp = Kgb + (size_t)((kt0+1)*64 + sr) * 2048 + sc;
            kA = *(const float4*)kp;  kB = *(const float4*)(kp + 8);
            const unsigned short* vp = Vgb + (size_t)sr * 2048 + (kt0+1)*64 + sc;
            vA = *(const float4*)vp;  vB = *(const float4*)(vp + 8);
        }
    }

    #pragma unroll
    for (int dt = 0; dt < 4; ++dt)
        #pragma unroll
        for (int r = 0; r < 4; ++r) oacc[dt][r] = 0.0f;
    float l_r = 0.0f;
    const int qg = qb*64 + w*16 + ln;

    __syncthreads();                    // buf0 visible; qf reads drained

    int cur = 0;
    for (int kt = kt0; kt <= kt1; ++kt) {
        const int co = cur ? KBUF : 0;      // compute buffer
        const int no = cur ? 0 : KBUF;      // next-tile buffer

        if (kt < kt1) {     // stage tile kt+1 into other buffer (readers drained
                            // by barrier of iter kt-1); drains under compute
            *(float4*)&Kt[no + swz64(sr, sc)]     = kA;
            *(float4*)&Kt[no + swz64(sr, sc + 8)] = kB;
            const ushort4* va4 = (const ushort4*)&vA;
            const ushort4* vb4 = (const ushort4*)&vB;
            *(ushort4*)&Vt[no + swz64(sr, ks*4 +  0)] = va4[0];
            *(ushort4*)&Vt[no + swz64(sr, ks*4 + 16)] = va4[1];
            *(ushort4*)&Vt[no + swz64(sr, ks*4 + 32)] = vb4[0];
            *(ushort4*)&Vt[no + swz64(sr, ks*4 + 48)] = vb4[1];
            if (kt + 1 < kt1) {             // prefetch regs for kt+2
                const unsigned short* kp = Kgb + (size_t)((kt+2)*64 + sr) * 2048 + sc;
                kA = *(const float4*)kp;  kB = *(const float4*)(kp + 8);
                const unsigned short* vp = Vgb + (size_t)sr * 2048 + (kt+2)*64 + sc;
                vA = *(const float4*)vp;  vB = *(const float4*)(vp + 8);
            }
        }

        // --- S^T = K Q^T  (reads buf[cur])
        f32x4 sacc[4];
        #pragma unroll
        for (int nt = 0; nt < 4; ++nt) {
            #pragma unroll
            for (int r = 0; r < 4; ++r) sacc[nt][r] = 0.0f;
            bf16x8 kf0 = *(const bf16x8*)&Kt[co + swz64(nt*16 + ln, lq*8)];
            bf16x8 kf1 = *(const bf16x8*)&Kt[co + swz64(nt*16 + ln, 32 + lq*8)];
            sacc[nt] = __builtin_amdgcn_mfma_f32_16x16x32_bf16(kf0, qf0, sacc[nt], 0, 0, 0);
            sacc[nt] = __builtin_amdgcn_mfma_f32_16x16x32_bf16(kf1, qf1, sacc[nt], 0, 0, 0);
        }

        // --- max-free softmax: p = exp2(min(s*scale, 50)); no cross-lane
        float p[16];
        if (kt == qb) {                     // diag tile: causal mask
            #pragma unroll
            for (int nt = 0; nt < 4; ++nt)
                #pragma unroll
                for (int r = 0; r < 4; ++r) {
                    float s = fminf(sacc[nt][r] * SCALE2, 50.0f);
                    if (kt*64 + nt*16 + lq*4 + r > qg) s = -INFINITY;
                    p[nt*4 + r] = __builtin_amdgcn_exp2f(s);
                }
        } else {
            #pragma unroll
            for (int i2 = 0; i2 < 16; ++i2) {
                const int nt = i2 >> 2, r = i2 & 3;
                p[i2] = __builtin_amdgcn_exp2f(fminf(sacc[nt][r] * SCALE2, 50.0f));
            }
        }
        float sum = 0.0f;
        #pragma unroll
        for (int i2 = 0; i2 < 16; ++i2) sum += p[i2];
        l_r += sum;

        // --- pack P^T (round-half-up via +0x8000, pack with v_perm)
        s16x4 pf[4];
        #pragma unroll
        for (int kk = 0; kk < 4; ++kk) {
            union { float f; unsigned u; } c0, c1, c2, c3;
            c0.f = p[kk*4+0]; c1.f = p[kk*4+1]; c2.f = p[kk*4+2]; c3.f = p[kk*4+3];
            unsigned lo = __builtin_amdgcn_perm(c1.u + 0x8000u, c0.u + 0x8000u, 0x07060302u);
            unsigned hi = __builtin_amdgcn_perm(c3.u + 0x8000u, c2.u + 0x8000u, 0x07060302u);
            union { unsigned u2[2]; s16x4 v; } pk;
            pk.u2[0] = lo; pk.u2[1] = hi;
            pf[kk] = pk.v;
        }

        // --- O^T += V^T P^T  (V-frags: 2 b128 per dt, reads buf[cur])
        #pragma unroll
        for (int dt = 0; dt < 4; ++dt) {
            union { bf16x8 v8; s16x4 h2[2]; } u01, u23;
            u01.v8 = *(const bf16x8*)&Vt[co + swz64(dt*16 + ln, lq*16)];
            u23.v8 = *(const bf16x8*)&Vt[co + swz64(dt*16 + ln, lq*16 + 8)];
            oacc[dt] = __builtin_amdgcn_mfma_f32_16x16x16bf16_1k(u01.h2[0], pf[0], oacc[dt], 0, 0, 0);
            oacc[dt] = __builtin_amdgcn_mfma_f32_16x16x16bf16_1k(u01.h2[1], pf[1], oacc[dt], 0, 0, 0);
            oacc[dt] = __builtin_amdgcn_mfma_f32_16x16x16bf16_1k(u23.h2[0], pf[2], oacc[dt], 0, 0, 0);
            oacc[dt] = __builtin_amdgcn_mfma_f32_16x16x16bf16_1k(u23.h2[1], pf[3], oacc[dt], 0, 0, 0);
        }

        __syncthreads();    // buf[no] visible; buf[cur] readers drained
        cur ^= 1;
    }

    l_r += __shfl_xor(l_r, 16);
    l_r += __shfl_xor(l_r, 32);
    return l_r;
}

// ---------------------------------------------------------------------------
// R13 flash: balanced split.  blockIdx.y = pair*2 + half.  For pair i:
//   h0: q-tile 31-i, KV tiles [0,16]           -> 17 tiles, partial -> buf 0
//   h1: q-tile 31-i, KV tiles [17, 31-i]       -> 15-i tiles, partial -> buf 1
//       + q-tile i full [0,i]                  -> i+1 tiles, final -> Ob
// Every block = 16-17 tile-iters.  Partials (f32, unnormalized) live in
// d_out (dead until O-proj); l partials in the dead xb region.
// ---------------------------------------------------------------------------
__global__ __launch_bounds__(256)
void flash_mfma_kernel(const unsigned short* __restrict__ QK,
                       const unsigned short* __restrict__ Vtg,
                       unsigned short* __restrict__ Ob,
                       float* __restrict__ Opart,
                       float* __restrict__ Lp)
{
    __shared__ unsigned short Kt[2 * 64 * 64];    // dbuf: Q/K tiles / O transpose
    __shared__ unsigned short Vt[2 * 64 * 64];    // dbuf: V^T tiles (permuted+swz)

    const int t    = threadIdx.x;
    const int w    = t >> 6;
    const int lane = t & 63;
    const int lq   = lane >> 4;
    const int ln   = lane & 15;
    const int bh   = blockIdx.x;
    const int yy   = blockIdx.y;
    const int ip   = yy >> 1;          // pair index 0..15
    const int hh   = yy & 1;
    const int b    = bh >> 4;
    const int hd   = bh & 15;
    const int qA   = 31 - ip;
    const int pidx = bh * 16 + ip;

    const unsigned short* Qg  = QK + hd*DK;                              // LD 2048
    const unsigned short* Kgb = QK + 1024 + hd*DK + (size_t)b*SEQ*2048;  // LD 2048
    const unsigned short* Vgb = Vtg + ((size_t)b*1024 + hd*DK) * 2048;   // [d][s]

    f32x4 oacc[4];

    if (hh == 0) {
        float l_r = flash_core(Qg + (size_t)(b*SEQ + qA*64)*2048, Kgb, Vgb,
                               Kt, Vt, qA, 0, 16, t, w, lq, ln, oacc);
        float* Op = Opart + (size_t)pidx * 4096 + (w*16 + ln)*64;
        #pragma unroll
        for (int dt = 0; dt < 4; ++dt)
            *(f32x4*)(Op + dt*16 + lq*4) = oacc[dt];
        if (lq == 0) Lp[pidx*64 + w*16 + ln] = l_r;
    } else {
        float l_r = flash_core(Qg + (size_t)(b*SEQ + qA*64)*2048, Kgb, Vgb,
                               Kt, Vt, qA, 17, qA, t, w, lq, ln, oacc);
        float* Op = Opart + (size_t)(512 + pidx) * 4096 + (w*16 + ln)*64;
        #pragma unroll
        for (int dt = 0; dt < 4; ++dt)
            *(f32x4*)(Op + dt*16 + lq*4) = oacc[dt];
        if (lq == 0) Lp[512*64 + pidx*64 + w*16 + ln] = l_r;

        __syncthreads();                // segment-1 done before Q restage
        const int qB = ip;
        l_r = flash_core(Qg + (size_t)(b*SEQ + qB*64)*2048, Kgb, Vgb,
                         Kt, Vt, qB, 0, qB, t, w, lq, ln, oacc);
        const float linv = 1.0f / l_r;
        __syncthreads();                // last tile reads done
        #pragma unroll
        for (int dt = 0; dt < 4; ++dt)
            #pragma unroll
            for (int r = 0; r < 4; ++r)
                Kt[swz64(w*16 + ln, dt*16 + lq*4 + r)] = f2bf(oacc[dt][r] * linv);
        __syncthreads();
        const int sr  = t >> 2;
        const int sc2 = (t & 3) * 16;
        unsigned short* op = Ob + (size_t)(b*SEQ + qB*64 + sr) * DMODEL + hd*DK + sc2;
        *(float4*)(op)     = *(const float4*)&Kt[swz64(sr, sc2)];
        *(float4*)(op + 8) = *(const float4*)&Kt[swz64(sr, sc2 + 8)];
    }
}

// ---------------------------------------------------------------------------
// combine split q-tiles: O = (O0+O1)/(l0+l1) -> bf16 Ob.  512 tiles.
// f32 2-way add is commutative -> deterministic regardless of block order.
// ---------------------------------------------------------------------------
__global__ __launch_bounds__(256)
void combine_kernel(const float* __restrict__ Opart,
                    const float* __restrict__ Lp,
                    unsigned short* __restrict__ Ob)
{
    const int pidx = blockIdx.x;            // 0..511
    const int bh = pidx >> 4, ip = pidx & 15;
    const int b  = bh >> 4,  hd = bh & 15;
    const int qA = 31 - ip;
    const int t  = threadIdx.x;
    const int q  = t >> 2;
    const int d0 = (t & 3) * 16;

    const float l   = Lp[pidx*64 + q] + Lp[512*64 + pidx*64 + q];
    const float inv = 1.0f / l;
    const float* O0 = Opart + (size_t)pidx * 4096 + q*64 + d0;
    const float* O1 = O0 + (size_t)512 * 4096;
    unsigned short* op = Ob + (size_t)(b*SEQ + qA*64 + q) * DMODEL + hd*DK + d0;
    #pragma unroll
    for (int j = 0; j < 4; ++j) {
        f32x4 a = *(const f32x4*)(O0 + j*4);
        f32x4 c = *(const f32x4*)(O1 + j*4);
        ushort4 o;
        o.x = f2bf((a[0] + c[0]) * inv);
        o.y = f2bf((a[1] + c[1]) * inv);
        o.z = f2bf((a[2] + c[2]) * inv);
        o.w = f2bf((a[3] + c[3]) * inv);
        *(ushort4*)(op + j*4) = o;
    }
}

// ---------------------------------------------------------------------------
extern "C" void kernel_launch(void* const* d_in, const int* in_sizes, int n_in,
                              void* d_out, int out_size, void* d_ws, size_t ws_size,
                              hipStream_t stream)
{
    const float* x  = (const float*)d_in[0];
    const float* Wq = (const float*)d_in[1];
    const float* Wk = (const float*)d_in[2];
    const float* Wv = (const float*)d_in[3];
    const float* Wo = (const float*)d_in[4];
    float* out = (float*)d_out;

    unsigned short* xb    = (unsigned short*)d_ws;   //  4M elems
    unsigned short* wqkvb = xb + 4194304;            //  3M
    unsigned short* wob   = wqkvb + 3145728;         //  1M
    unsigned short* qk    = wob + 1048576;           //  8M  [4096][2048]
    unsigned short* vt    = qk + 8388608;            //  4M  [2][1024][2048]
    unsigned short* ob    = vt + 4194304;            //  4M  [4096][1024]
    // total 24M elems = 48 MB
    // O partials (2 x 512 x 64x64 f32 = 16 MB) live in d_out (dead until
    // O-proj overwrites it); l partials (256 KB) live in xb (dead after QKV).

    convert_kernel<<<4096, 256, 0, stream>>>(x, Wq, Wk, Wv, Wo, xb, wqkvb, wob);

    // QKV: 128x128 tiles, grid (24,32) = 768 blocks = 3/CU exact
    gemm_mfma_bt<128, 128, 2048, 1, 3><<<dim3(24, 32), 256, 0, stream>>>(xb, wqkvb, qk, vt);

    // balanced flash: 32 bh x (16 pairs x 2 halves)
    flash_mfma_kernel<<<dim3(32, 32), 256, 0, stream>>>(qk, vt, ob,
                                                        (float*)out, (float*)xb);

    combine_kernel<<<512, 256, 0, stream>>>((const float*)out, (const float*)xb, ob);

    // O-proj: 128x64 tiles, grid (16,32) = 512 blocks = 2/CU
    gemm_mfma_bt<128, 64, 1024, 0, 2><<<dim3(16, 32), 256, 0, stream>>>(ob, wob, out, nullptr);
}

// Round 5
// 170.815 us; speedup vs baseline: 1.0243x; 1.0243x over previous
//
#include <hip/hip_runtime.h>
#include <cmath>

#define SEQ    2048
#define DMODEL 1024
#define NHEADS 16
#define DK     64
#define MROWS  4096   // B*S
#define KBUF   4096   // flash LDS double-buffer offset (64*64 shorts)

typedef __bf16 bf16x8 __attribute__((ext_vector_type(8)));
typedef float  f32x4  __attribute__((ext_vector_type(4)));
typedef short  s16x4  __attribute__((ext_vector_type(4)));

__device__ __forceinline__ unsigned short f2bf(float f) {
    union { float f; unsigned u; } v; v.f = f;
    unsigned r = v.u + 0x7fffu + ((v.u >> 16) & 1u);   // RNE
    return (unsigned short)(r >> 16);
}

__device__ __forceinline__ void async16(const unsigned short* g, unsigned short* l) {
    __builtin_amdgcn_global_load_lds(
        (const __attribute__((address_space(1))) unsigned int*)(g),
        (__attribute__((address_space(3))) unsigned int*)(l),
        16, 0, 0);
}

// XOR-granule swizzle: pitch 64 shorts, 8-short (16B) granules, granule g of
// row r lives at slot g ^ (r&7).  All flash LDS accesses map 8 lanes to each
// 4-bank group per op -> conflict-free (R13: was 5.5M conflict cycles).
__device__ __forceinline__ int swz64(int row, int col) {
    return (row << 6) + ((((col >> 3) ^ row) & 7) << 3) + (col & 7);
}

// ---------------------------------------------------------------------------
// fp32 -> bf16 conversion of x, Wq|Wk|Wv (packed), Wo
// ---------------------------------------------------------------------------
__global__ __launch_bounds__(256)
void convert_kernel(const float* __restrict__ x,
                    const float* __restrict__ wq, const float* __restrict__ wk,
                    const float* __restrict__ wv, const float* __restrict__ wo,
                    unsigned short* __restrict__ xb,
                    unsigned short* __restrict__ wqkvb,
                    unsigned short* __restrict__ wob)
{
    const unsigned e = (blockIdx.x * 256u + threadIdx.x) * 8u;
    const float* src; unsigned short* dst; unsigned off;
    if      (e < 4194304u) { src = x;  dst = xb;             off = e;            }
    else if (e < 5242880u) { src = wq; dst = wqkvb;          off = e - 4194304u; }
    else if (e < 6291456u) { src = wk; dst = wqkvb+1048576u; off = e - 5242880u; }
    else if (e < 7340032u) { src = wv; dst = wqkvb+2097152u; off = e - 6291456u; }
    else                   { src = wo; dst = wob;            off = e - 7340032u; }
    float4 a = *(const float4*)(src + off);
    float4 b = *(const float4*)(src + off + 4);
    ushort4 u0, u1;
    u0.x=f2bf(a.x); u0.y=f2bf(a.y); u0.z=f2bf(a.z); u0.w=f2bf(a.w);
    u1.x=f2bf(b.x); u1.y=f2bf(b.y); u1.z=f2bf(b.z); u1.w=f2bf(b.w);
    *(ushort4*)(dst + off)     = u0;
    *(ushort4*)(dst + off + 4) = u1;
}

// ---------------------------------------------------------------------------
// bf16 MFMA GEMM: Y = A[M][1024] @ B[NCOLS][1024]^T.  TM x TN tiles, BK=64,
// single-buffered async16 (m97 structure).  MINW = launch_bounds min waves/EU.
// QKV: 128x128 @ 3/CU.  O-proj: 128x64 @ 2/CU.
// R16: RoPE epilogue uses angle-addition recurrence -- 20 sincosf/thread
// (4 delta + 16 base) instead of 64; r=1..3 rotated by (cos fr, sin fr)
// with 4 FMA/step.  Rotation drift ~1e-7 << bf16 ulp.
// MODE 0: fp32 row-major out (O-proj).
// MODE 1: QKV split: cols <2048 -> RoPE + bf16 QK buf; cols >=2048 -> V^T.
// ---------------------------------------------------------------------------
template<int TM, int TN, int NCOLS, int MODE, int MINW>
__global__ __launch_bounds__(256, MINW)
void gemm_mfma_bt(const unsigned short* __restrict__ A,
                  const unsigned short* __restrict__ B,
                  void* __restrict__ Yqk,
                  unsigned short* __restrict__ Yvt)
{
    constexpr int AINST = TM / 32;      // A async16 insts per thread
    constexpr int BINST = TN / 32;      // B async16 insts per thread
    constexpr int MT    = TM / 32;      // 16-row frags per wave (TM/2 /16)
    constexpr int NT    = TN / 32;      // 16-col frags per wave

    __shared__ unsigned short As[TM * 64];
    __shared__ unsigned short Bs[TN * 64];

    const int t    = threadIdx.x;
    const int w    = t >> 6;
    const int lane = t & 63;
    const int lq   = lane >> 4;
    const int ln   = lane & 15;
    const int m0   = blockIdx.y * TM;
    const int n0   = blockIdx.x * TN;

    const int mrow0 = (w & 1) * (TM / 2);      // wave tile: TM/2 x TN/2
    const int ncol0 = (w >> 1) * (TN / 2);

    const int srow  = w*8 + (lane >> 3);
    const int gslot = (lane & 7) ^ (lane >> 3);

    const unsigned short* gA[AINST]; unsigned short* lA[AINST];
    #pragma unroll
    for (int i = 0; i < AINST; ++i) {
        gA[i] = A + (size_t)(m0 + i*32 + srow) * 1024 + gslot*8;
        lA[i] = As + (i*32 + w*8) * 64;
    }
    const unsigned short* gB[BINST]; unsigned short* lB[BINST];
    #pragma unroll
    for (int i = 0; i < BINST; ++i) {
        gB[i] = B + (size_t)(n0 + i*32 + srow) * 1024 + gslot*8;
        lB[i] = Bs + (i*32 + w*8) * 64;
    }

    f32x4 acc[MT][NT];
    #pragma unroll
    for (int mt = 0; mt < MT; ++mt)
        #pragma unroll
        for (int nt = 0; nt < NT; ++nt)
            #pragma unroll
            for (int r = 0; r < 4; ++r) acc[mt][nt][r] = 0.0f;

    const int fsw = (ln & 7);

    for (int k0 = 0; k0 < 1024; k0 += 64) {
        __syncthreads();
        #pragma unroll
        for (int i = 0; i < AINST; ++i) async16(gA[i] + k0, lA[i]);
        #pragma unroll
        for (int i = 0; i < BINST; ++i) async16(gB[i] + k0, lB[i]);
        __syncthreads();
        #pragma unroll
        for (int kh = 0; kh < 2; ++kh) {
            const int g  = kh*4 + lq;
            const int ps = (g ^ fsw) * 8;
            bf16x8 af[MT], bf[NT];
            #pragma unroll
            for (int mt = 0; mt < MT; ++mt)
                af[mt] = *(const bf16x8*)&As[(mrow0 + mt*16 + ln)*64 + ps];
            #pragma unroll
            for (int nt = 0; nt < NT; ++nt)
                bf[nt] = *(const bf16x8*)&Bs[(ncol0 + nt*16 + ln)*64 + ps];
            #pragma unroll
            for (int mt = 0; mt < MT; ++mt)
                #pragma unroll
                for (int nt = 0; nt < NT; ++nt)
                    acc[mt][nt] = __builtin_amdgcn_mfma_f32_16x16x32_bf16(
                                      af[mt], bf[nt], acc[mt][nt], 0, 0, 0);
        }
    }

    if (MODE == 0) {
        float* Yf = (float*)Yqk;
        #pragma unroll
        for (int nt = 0; nt < NT; ++nt) {
            const int col = n0 + ncol0 + nt*16 + ln;
            #pragma unroll
            for (int mt = 0; mt < MT; ++mt) {
                const int row0 = m0 + mrow0 + mt*16 + lq*4;
                #pragma unroll
                for (int r = 0; r < 4; ++r)
                    Yf[(size_t)(row0 + r) * NCOLS + col] = acc[mt][nt][r];
            }
        }
    } else if (n0 < 2048) {
        // QK region: RoPE via rotation recurrence, bf16 row-major LD 2048
        unsigned short* Yb = (unsigned short*)Yqk;
        const float LOG_T = 9.210340371976184f / 32.0f;
        #pragma unroll
        for (int nt = 0; nt < NT; ++nt) {
            const int col = n0 + ncol0 + nt*16 + ln;
            const float fr = __expf(-(float)((col & 63) >> 1) * LOG_T);
            float sd, cd;
            __sincosf(fr, &sd, &cd);           // per-row rotation delta
            #pragma unroll
            for (int mt = 0; mt < MT; ++mt) {
                const int row0 = m0 + mrow0 + mt*16 + lq*4;
                float sn, cs;
                __sincosf((float)(row0 & (SEQ - 1)) * fr, &sn, &cs);
                #pragma unroll
                for (int r = 0; r < 4; ++r) {
                    const float v = acc[mt][nt][r];
                    const float p = __shfl_xor(v, 1);
                    const float outv = ((ln & 1) == 0) ? (v*cs - p*sn) : (p*sn + v*cs);
                    Yb[(size_t)(row0 + r) * 2048 + col] = f2bf(outv);
                    const float cs2 = cs*cd - sn*sd;   // rotate angle by fr
                    sn = sn*cd + cs*sd;
                    cs = cs2;
                }
            }
        }
    } else {
        // V region: write transposed [b][d][s]; lane's 4 rows contiguous in s
        #pragma unroll
        for (int nt = 0; nt < NT; ++nt) {
            const int d = (n0 - 2048) + ncol0 + nt*16 + ln;
            #pragma unroll
            for (int mt = 0; mt < MT; ++mt) {
                const int row0 = m0 + mrow0 + mt*16 + lq*4;
                const int b = row0 >> 11;
                const int s = row0 & 2047;
                ushort4 o;
                o.x = f2bf(acc[mt][nt][0]); o.y = f2bf(acc[mt][nt][1]);
                o.z = f2bf(acc[mt][nt][2]); o.w = f2bf(acc[mt][nt][3]);
                *(ushort4*)&Yvt[((size_t)b*1024 + d) * 2048 + s] = o;
            }
        }
    }
}

// ---------------------------------------------------------------------------
// R15 flash core: double-buffered K/V LDS, ONE barrier per KV tile.
// Iter kt: write tile kt+1 -> buf[cur^1] (safe: barrier(kt-1) drained its
// readers), prefetch regs kt+2, compute on buf[cur], barrier, swap.
// Q staged in buf1; its reads complete before buf1's first write (2nd
// prologue barrier).  Max-free softmax -> partials are pure sums.
// ---------------------------------------------------------------------------
__device__ __forceinline__ float flash_core(
    const unsigned short* __restrict__ Qrow,   // Q base of this q-tile (LD 2048)
    const unsigned short* __restrict__ Kgb,    // K base for this b (LD 2048)
    const unsigned short* __restrict__ Vgb,    // V^T base for this (b,head)
    unsigned short* Kt, unsigned short* Vt,    // each 2 x 64 x 64
    const int qb, const int kt0, const int kt1,   // kt range inclusive; kt1<kt0 => empty
    const int t, const int w, const int lq, const int ln,
    f32x4 (&oacc)[4])
{
    const int sr = t >> 2;            // staging row 0..63
    const int sc = (t & 3) * 16;      // staging col 0,16,32,48
    const int ks = t & 3;             // this thread's key-subtile for V staging
    const float SCALE2 = 0.125f * 1.4426950408889634f;   // 1/sqrt(dk) * log2e
    const bool any = (kt0 <= kt1);

    {   // stage Q tile -> Kt buf1 (first K-write to buf1 is iter kt0+1)
        const unsigned short* qp = Qrow + (size_t)sr * 2048 + sc;
        *(float4*)&Kt[KBUF + swz64(sr, sc)]     = *(const float4*)qp;
        *(float4*)&Kt[KBUF + swz64(sr, sc + 8)] = *(const float4*)(qp + 8);
    }
    float4 kA, kB, vA, vB;
    if (any) {   // preload first K/V^T tile into registers
        const unsigned short* kp = Kgb + (size_t)(kt0*64 + sr) * 2048 + sc;
        kA = *(const float4*)kp;  kB = *(const float4*)(kp + 8);
        const unsigned short* vp = Vgb + (size_t)sr * 2048 + kt0*64 + sc;
        vA = *(const float4*)vp;  vB = *(const float4*)(vp + 8);
    }
    __syncthreads();                    // Q visible
    const bf16x8 qf0 = *(const bf16x8*)&Kt[KBUF + swz64(w*16 + ln, lq*8)];
    const bf16x8 qf1 = *(const bf16x8*)&Kt[KBUF + swz64(w*16 + ln, 32 + lq*8)];

    if (any) {   // write tile kt0 -> buf0 (disjoint from Q reads in buf1)
        *(float4*)&Kt[swz64(sr, sc)]     = kA;
        *(float4*)&Kt[swz64(sr, sc + 8)] = kB;
        const ushort4* va4 = (const ushort4*)&vA;
        const ushort4* vb4 = (const ushort4*)&vB;
        *(ushort4*)&Vt[swz64(sr, ks*4 +  0)] = va4[0];
        *(ushort4*)&Vt[swz64(sr, ks*4 + 16)] = va4[1];
        *(ushort4*)&Vt[swz64(sr, ks*4 + 32)] = vb4[0];
        *(ushort4*)&Vt[swz64(sr, ks*4 + 48)] = vb4[1];
        if (kt0 < kt1) {                // preload regs for kt0+1
            const unsigned short* kp = Kgb + (size_t)((kt0+1)*64 + sr) * 2048 + sc;
            kA = *(const float4*)kp;  kB = *(const float4*)(kp + 8);
            const unsigned short* vp = Vgb + (size_t)sr * 2048 + (kt0+1)*64 + sc;
            vA = *(const float4*)vp;  vB = *(const float4*)(vp + 8);
        }
    }

    #pragma unroll
    for (int dt = 0; dt < 4; ++dt)
        #pragma unroll
        for (int r = 0; r < 4; ++r) oacc[dt][r] = 0.0f;
    float l_r = 0.0f;
    const int qg = qb*64 + w*16 + ln;

    __syncthreads();                    // buf0 visible; qf reads drained

    int cur = 0;
    for (int kt = kt0; kt <= kt1; ++kt) {
        const int co = cur ? KBUF : 0;      // compute buffer
        const int no = cur ? 0 : KBUF;      // next-tile buffer

        if (kt < kt1) {     // stage tile kt+1 into other buffer (readers drained
                            // by barrier of iter kt-1); drains under compute
            *(float4*)&Kt[no + swz64(sr, sc)]     = kA;
            *(float4*)&Kt[no + swz64(sr, sc + 8)] = kB;
            const ushort4* va4 = (const ushort4*)&vA;
            const ushort4* vb4 = (const ushort4*)&vB;
            *(ushort4*)&Vt[no + swz64(sr, ks*4 +  0)] = va4[0];
            *(ushort4*)&Vt[no + swz64(sr, ks*4 + 16)] = va4[1];
            *(ushort4*)&Vt[no + swz64(sr, ks*4 + 32)] = vb4[0];
            *(ushort4*)&Vt[no + swz64(sr, ks*4 + 48)] = vb4[1];
            if (kt + 1 < kt1) {             // prefetch regs for kt+2
                const unsigned short* kp = Kgb + (size_t)((kt+2)*64 + sr) * 2048 + sc;
                kA = *(const float4*)kp;  kB = *(const float4*)(kp + 8);
                const unsigned short* vp = Vgb + (size_t)sr * 2048 + (kt+2)*64 + sc;
                vA = *(const float4*)vp;  vB = *(const float4*)(vp + 8);
            }
        }

        // --- S^T = K Q^T  (reads buf[cur])
        f32x4 sacc[4];
        #pragma unroll
        for (int nt = 0; nt < 4; ++nt) {
            #pragma unroll
            for (int r = 0; r < 4; ++r) sacc[nt][r] = 0.0f;
            bf16x8 kf0 = *(const bf16x8*)&Kt[co + swz64(nt*16 + ln, lq*8)];
            bf16x8 kf1 = *(const bf16x8*)&Kt[co + swz64(nt*16 + ln, 32 + lq*8)];
            sacc[nt] = __builtin_amdgcn_mfma_f32_16x16x32_bf16(kf0, qf0, sacc[nt], 0, 0, 0);
            sacc[nt] = __builtin_amdgcn_mfma_f32_16x16x32_bf16(kf1, qf1, sacc[nt], 0, 0, 0);
        }

        // --- max-free softmax: p = exp2(min(s*scale, 50)); no cross-lane
        float p[16];
        if (kt == qb) {                     // diag tile: causal mask
            #pragma unroll
            for (int nt = 0; nt < 4; ++nt)
                #pragma unroll
                for (int r = 0; r < 4; ++r) {
                    float s = fminf(sacc[nt][r] * SCALE2, 50.0f);
                    if (kt*64 + nt*16 + lq*4 + r > qg) s = -INFINITY;
                    p[nt*4 + r] = __builtin_amdgcn_exp2f(s);
                }
        } else {
            #pragma unroll
            for (int i2 = 0; i2 < 16; ++i2) {
                const int nt = i2 >> 2, r = i2 & 3;
                p[i2] = __builtin_amdgcn_exp2f(fminf(sacc[nt][r] * SCALE2, 50.0f));
            }
        }
        float sum = 0.0f;
        #pragma unroll
        for (int i2 = 0; i2 < 16; ++i2) sum += p[i2];
        l_r += sum;

        // --- pack P^T (round-half-up via +0x8000, pack with v_perm)
        s16x4 pf[4];
        #pragma unroll
        for (int kk = 0; kk < 4; ++kk) {
            union { float f; unsigned u; } c0, c1, c2, c3;
            c0.f = p[kk*4+0]; c1.f = p[kk*4+1]; c2.f = p[kk*4+2]; c3.f = p[kk*4+3];
            unsigned lo = __builtin_amdgcn_perm(c1.u + 0x8000u, c0.u + 0x8000u, 0x07060302u);
            unsigned hi = __builtin_amdgcn_perm(c3.u + 0x8000u, c2.u + 0x8000u, 0x07060302u);
            union { unsigned u2[2]; s16x4 v; } pk;
            pk.u2[0] = lo; pk.u2[1] = hi;
            pf[kk] = pk.v;
        }

        // --- O^T += V^T P^T  (V-frags: 2 b128 per dt, reads buf[cur])
        #pragma unroll
        for (int dt = 0; dt < 4; ++dt) {
            union { bf16x8 v8; s16x4 h2[2]; } u01, u23;
            u01.v8 = *(const bf16x8*)&Vt[co + swz64(dt*16 + ln, lq*16)];
            u23.v8 = *(const bf16x8*)&Vt[co + swz64(dt*16 + ln, lq*16 + 8)];
            oacc[dt] = __builtin_amdgcn_mfma_f32_16x16x16bf16_1k(u01.h2[0], pf[0], oacc[dt], 0, 0, 0);
            oacc[dt] = __builtin_amdgcn_mfma_f32_16x16x16bf16_1k(u01.h2[1], pf[1], oacc[dt], 0, 0, 0);
            oacc[dt] = __builtin_amdgcn_mfma_f32_16x16x16bf16_1k(u23.h2[0], pf[2], oacc[dt], 0, 0, 0);
            oacc[dt] = __builtin_amdgcn_mfma_f32_16x16x16bf16_1k(u23.h2[1], pf[3], oacc[dt], 0, 0, 0);
        }

        __syncthreads();    // buf[no] visible; buf[cur] readers drained
        cur ^= 1;
    }

    l_r += __shfl_xor(l_r, 16);
    l_r += __shfl_xor(l_r, 32);
    return l_r;
}

// ---------------------------------------------------------------------------
// R13 flash: balanced split.  blockIdx.y = pair*2 + half.  For pair i:
//   h0: q-tile 31-i, KV tiles [0,16]           -> 17 tiles, partial -> buf 0
//   h1: q-tile 31-i, KV tiles [17, 31-i]       -> 15-i tiles, partial -> buf 1
//       + q-tile i full [0,i]                  -> i+1 tiles, final -> Ob
// Every block = 16-17 tile-iters.  Partials (f32, unnormalized) live in
// d_out (dead until O-proj); l partials in the dead xb region.
// ---------------------------------------------------------------------------
__global__ __launch_bounds__(256)
void flash_mfma_kernel(const unsigned short* __restrict__ QK,
                       const unsigned short* __restrict__ Vtg,
                       unsigned short* __restrict__ Ob,
                       float* __restrict__ Opart,
                       float* __restrict__ Lp)
{
    __shared__ unsigned short Kt[2 * 64 * 64];    // dbuf: Q/K tiles / O transpose
    __shared__ unsigned short Vt[2 * 64 * 64];    // dbuf: V^T tiles (permuted+swz)

    const int t    = threadIdx.x;
    const int w    = t >> 6;
    const int lane = t & 63;
    const int lq   = lane >> 4;
    const int ln   = lane & 15;
    const int bh   = blockIdx.x;
    const int yy   = blockIdx.y;
    const int ip   = yy >> 1;          // pair index 0..15
    const int hh   = yy & 1;
    const int b    = bh >> 4;
    const int hd   = bh & 15;
    const int qA   = 31 - ip;
    const int pidx = bh * 16 + ip;

    const unsigned short* Qg  = QK + hd*DK;                              // LD 2048
    const unsigned short* Kgb = QK + 1024 + hd*DK + (size_t)b*SEQ*2048;  // LD 2048
    const unsigned short* Vgb = Vtg + ((size_t)b*1024 + hd*DK) * 2048;   // [d][s]

    f32x4 oacc[4];

    if (hh == 0) {
        float l_r = flash_core(Qg + (size_t)(b*SEQ + qA*64)*2048, Kgb, Vgb,
                               Kt, Vt, qA, 0, 16, t, w, lq, ln, oacc);
        float* Op = Opart + (size_t)pidx * 4096 + (w*16 + ln)*64;
        #pragma unroll
        for (int dt = 0; dt < 4; ++dt)
            *(f32x4*)(Op + dt*16 + lq*4) = oacc[dt];
        if (lq == 0) Lp[pidx*64 + w*16 + ln] = l_r;
    } else {
        float l_r = flash_core(Qg + (size_t)(b*SEQ + qA*64)*2048, Kgb, Vgb,
                               Kt, Vt, qA, 17, qA, t, w, lq, ln, oacc);
        float* Op = Opart + (size_t)(512 + pidx) * 4096 + (w*16 + ln)*64;
        #pragma unroll
        for (int dt = 0; dt < 4; ++dt)
            *(f32x4*)(Op + dt*16 + lq*4) = oacc[dt];
        if (lq == 0) Lp[512*64 + pidx*64 + w*16 + ln] = l_r;

        __syncthreads();                // segment-1 done before Q restage
        const int qB = ip;
        l_r = flash_core(Qg + (size_t)(b*SEQ + qB*64)*2048, Kgb, Vgb,
                         Kt, Vt, qB, 0, qB, t, w, lq, ln, oacc);
        const float linv = 1.0f / l_r;
        __syncthreads();                // last tile reads done
        #pragma unroll
        for (int dt = 0; dt < 4; ++dt)
            #pragma unroll
            for (int r = 0; r < 4; ++r)
                Kt[swz64(w*16 + ln, dt*16 + lq*4 + r)] = f2bf(oacc[dt][r] * linv);
        __syncthreads();
        const int sr  = t >> 2;
        const int sc2 = (t & 3) * 16;
        unsigned short* op = Ob + (size_t)(b*SEQ + qB*64 + sr) * DMODEL + hd*DK + sc2;
        *(float4*)(op)     = *(const float4*)&Kt[swz64(sr, sc2)];
        *(float4*)(op + 8) = *(const float4*)&Kt[swz64(sr, sc2 + 8)];
    }
}

// ---------------------------------------------------------------------------
// combine split q-tiles: O = (O0+O1)/(l0+l1) -> bf16 Ob.  512 tiles.
// f32 2-way add is commutative -> deterministic regardless of block order.
// ---------------------------------------------------------------------------
__global__ __launch_bounds__(256)
void combine_kernel(const float* __restrict__ Opart,
                    const float* __restrict__ Lp,
                    unsigned short* __restrict__ Ob)
{
    const int pidx = blockIdx.x;            // 0..511
    const int bh = pidx >> 4, ip = pidx & 15;
    const int b  = bh >> 4,  hd = bh & 15;
    const int qA = 31 - ip;
    const int t  = threadIdx.x;
    const int q  = t >> 2;
    const int d0 = (t & 3) * 16;

    const float l   = Lp[pidx*64 + q] + Lp[512*64 + pidx*64 + q];
    const float inv = 1.0f / l;
    const float* O0 = Opart + (size_t)pidx * 4096 + q*64 + d0;
    const float* O1 = O0 + (size_t)512 * 4096;
    unsigned short* op = Ob + (size_t)(b*SEQ + qA*64 + q) * DMODEL + hd*DK + d0;
    #pragma unroll
    for (int j = 0; j < 4; ++j) {
        f32x4 a = *(const f32x4*)(O0 + j*4);
        f32x4 c = *(const f32x4*)(O1 + j*4);
        ushort4 o;
        o.x = f2bf((a[0] + c[0]) * inv);
        o.y = f2bf((a[1] + c[1]) * inv);
        o.z = f2bf((a[2] + c[2]) * inv);
        o.w = f2bf((a[3] + c[3]) * inv);
        *(ushort4*)(op + j*4) = o;
    }
}

// ---------------------------------------------------------------------------
extern "C" void kernel_launch(void* const* d_in, const int* in_sizes, int n_in,
                              void* d_out, int out_size, void* d_ws, size_t ws_size,
                              hipStream_t stream)
{
    const float* x  = (const float*)d_in[0];
    const float* Wq = (const float*)d_in[1];
    const float* Wk = (const float*)d_in[2];
    const float* Wv = (const float*)d_in[3];
    const float* Wo = (const float*)d_in[4];
    float* out = (float*)d_out;

    unsigned short* xb    = (unsigned short*)d_ws;   //  4M elems
    unsigned short* wqkvb = xb + 4194304;            //  3M
    unsigned short* wob   = wqkvb + 3145728;         //  1M
    unsigned short* qk    = wob + 1048576;           //  8M  [4096][2048]
    unsigned short* vt    = qk + 8388608;            //  4M  [2][1024][2048]
    unsigned short* ob    = vt + 4194304;            //  4M  [4096][1024]
    // total 24M elems = 48 MB
    // O partials (2 x 512 x 64x64 f32 = 16 MB) live in d_out (dead until
    // O-proj overwrites it); l partials (256 KB) live in xb (dead after QKV).

    convert_kernel<<<4096, 256, 0, stream>>>(x, Wq, Wk, Wv, Wo, xb, wqkvb, wob);

    // QKV: 128x128 tiles, grid (24,32) = 768 blocks = 3/CU exact
    gemm_mfma_bt<128, 128, 2048, 1, 3><<<dim3(24, 32), 256, 0, stream>>>(xb, wqkvb, qk, vt);

    // balanced flash: 32 bh x (16 pairs x 2 halves)
    flash_mfma_kernel<<<dim3(32, 32), 256, 0, stream>>>(qk, vt, ob,
                                                        (float*)out, (float*)xb);

    combine_kernel<<<512, 256, 0, stream>>>((const float*)out, (const float*)xb, ob);

    // O-proj: 128x64 tiles, grid (16,32) = 512 blocks = 2/CU
    gemm_mfma_bt<128, 64, 1024, 0, 2><<<dim3(16, 32), 256, 0, stream>>>(ob, wob, out, nullptr);
}